// Round 3
// baseline (1854.634 us; speedup 1.0000x reference)
//
#include <hip/hip_runtime.h>
#include <hip/hip_bf16.h>
#include <math.h>

// ---------------- constants ----------------
#define B_     16
#define NTOK   1024
#define DIM_   384
#define DEPTH_ 6
#define HEADS_ 6
#define DH_    64
#define MLP_   1536
#define MTOT   (B_ * NTOK)    // 16384 tokens
#define NBH    (B_ * HEADS_)  // 96 batch-heads

typedef unsigned short u16;
typedef short short8 __attribute__((ext_vector_type(8)));
typedef float f32x4 __attribute__((ext_vector_type(4)));

static __device__ __forceinline__ u16 f2b(float f) {
    __hip_bfloat16 h = __float2bfloat16(f);
    return *reinterpret_cast<u16*>(&h);
}

// ---------------- weight transpose + bf16 convert ----------------
// W[K][N] fp32 (per layer) -> WT[N][K] bf16.  Tile 64x64, block 256.
__launch_bounds__(256)
__global__ void transpose_w_kernel(const float* __restrict__ W, u16* __restrict__ WT,
                                   int K, int N) {
    const int layer = blockIdx.z;
    W  += (size_t)layer * K * N;
    WT += (size_t)layer * K * N;
    __shared__ u16 tile[64 * 72];
    const int t = threadIdx.x;
    const int k0 = blockIdx.x * 64, n0 = blockIdx.y * 64;
    const int row = t >> 2, cs = (t & 3) * 16;
    const float4* src = reinterpret_cast<const float4*>(W + (size_t)(k0 + row) * N + n0 + cs);
#pragma unroll
    for (int i = 0; i < 4; i++) {
        float4 f = src[i];
        tile[row * 72 + cs + i * 4 + 0] = f2b(f.x);
        tile[row * 72 + cs + i * 4 + 1] = f2b(f.y);
        tile[row * 72 + cs + i * 4 + 2] = f2b(f.z);
        tile[row * 72 + cs + i * 4 + 3] = f2b(f.w);
    }
    __syncthreads();
    const int nrow = row, ks = cs;
    u16 vals[16] __attribute__((aligned(16)));
#pragma unroll
    for (int e = 0; e < 16; e++) vals[e] = tile[(ks + e) * 72 + nrow];
    u16* dst = WT + (size_t)(n0 + nrow) * K + k0 + ks;
    *reinterpret_cast<short8*>(dst)     = *reinterpret_cast<short8*>(&vals[0]);
    *reinterpret_cast<short8*>(dst + 8) = *reinterpret_cast<short8*>(&vals[8]);
}

// ---------------- LayerNorm: fp32 x -> bf16 h ----------------
// one wave per token, 4 tokens per block
__launch_bounds__(256)
__global__ void ln_kernel(const float* __restrict__ x, const float* __restrict__ g,
                          const float* __restrict__ b, u16* __restrict__ h) {
    const int tok  = blockIdx.x * 4 + (threadIdx.x >> 6);
    const int lane = threadIdx.x & 63;
    const float* xr = x + (size_t)tok * DIM_;
    float v[6];
    float s = 0.f;
#pragma unroll
    for (int i = 0; i < 6; i++) { v[i] = xr[lane + i * 64]; s += v[i]; }
#pragma unroll
    for (int m = 1; m < 64; m <<= 1) s += __shfl_xor(s, m);
    const float mean = s * (1.f / 384.f);
    float qs = 0.f;
#pragma unroll
    for (int i = 0; i < 6; i++) { float d = v[i] - mean; qs += d * d; }
#pragma unroll
    for (int m = 1; m < 64; m <<= 1) qs += __shfl_xor(qs, m);
    const float inv = rsqrtf(qs * (1.f / 384.f) + 1e-5f);
    u16* hr = h + (size_t)tok * DIM_;
#pragma unroll
    for (int i = 0; i < 6; i++) {
        const int c = lane + i * 64;
        hr[c] = f2b((v[i] - mean) * inv * g[c] + b[c]);
    }
}

// ---------------- generic bf16 MFMA GEMM ----------------
// C[M,N] = A[M,K] @ B[K,N], A row-major bf16, BT = B^T [N][K] bf16.
// 128x128 tile, 4 waves (2x2), each wave 64x64 (4x4 frags of 16x16), BK=32.
enum { EPI_QKV = 0, EPI_RES = 1, EPI_GELU = 2 };

template <int EPI>
__launch_bounds__(256)
__global__ void gemm_kernel(const u16* __restrict__ A, const u16* __restrict__ BT, int K,
                            const float* __restrict__ bias, const float* __restrict__ resid,
                            float* __restrict__ outf, u16* __restrict__ outb, int ldc,
                            u16* __restrict__ qkv_base) {
    __shared__ u16 As[128 * 40];
    __shared__ u16 Bs[128 * 40];
    const int t = threadIdx.x;
    const int lane = t & 63, w = t >> 6;
    const int wm = w >> 1, wn = w & 1;
    const int m0 = blockIdx.x * 128, n0 = blockIdx.y * 128;

    f32x4 acc[4][4] = {};

    const int srow = t >> 1, sseg = t & 1;
    const u16* agp = A  + (size_t)(m0 + srow) * K + sseg * 16;
    const u16* bgp = BT + (size_t)(n0 + srow) * K + sseg * 16;
    u16* asl = &As[srow * 40 + sseg * 16];
    u16* bsl = &Bs[srow * 40 + sseg * 16];

    for (int kk = 0; kk < K; kk += 32) {
        __syncthreads();
        *reinterpret_cast<short8*>(asl)     = *reinterpret_cast<const short8*>(agp + kk);
        *reinterpret_cast<short8*>(asl + 8) = *reinterpret_cast<const short8*>(agp + kk + 8);
        *reinterpret_cast<short8*>(bsl)     = *reinterpret_cast<const short8*>(bgp + kk);
        *reinterpret_cast<short8*>(bsl + 8) = *reinterpret_cast<const short8*>(bgp + kk + 8);
        __syncthreads();
        short8 af[4], bf[4];
#pragma unroll
        for (int i = 0; i < 4; i++)
            af[i] = *reinterpret_cast<const short8*>(
                &As[(wm * 64 + i * 16 + (lane & 15)) * 40 + (lane >> 4) * 8]);
#pragma unroll
        for (int j = 0; j < 4; j++)
            bf[j] = *reinterpret_cast<const short8*>(
                &Bs[(wn * 64 + j * 16 + (lane & 15)) * 40 + (lane >> 4) * 8]);
#pragma unroll
        for (int i = 0; i < 4; i++)
#pragma unroll
            for (int j = 0; j < 4; j++)
                acc[i][j] = __builtin_amdgcn_mfma_f32_16x16x32_bf16(af[i], bf[j], acc[i][j], 0, 0, 0);
    }

    // epilogue: D layout col=lane&15, row=(lane>>4)*4+reg
    const int rbase = (lane >> 4) * 4;
    const int cb = lane & 15;
#pragma unroll
    for (int i = 0; i < 4; i++) {
#pragma unroll
        for (int j = 0; j < 4; j++) {
#pragma unroll
            for (int r = 0; r < 4; r++) {
                const int m = m0 + wm * 64 + i * 16 + rbase + r;
                const int c = n0 + wn * 64 + j * 16 + cb;
                const float val = acc[i][j][r];
                if constexpr (EPI == EPI_QKV) {
                    const int which = c / 384;
                    const int cc = c - which * 384;
                    const int head = cc >> 6, dh = cc & 63;
                    const int b = m >> 10, n = m & 1023;
                    qkv_base[(size_t)which * ((size_t)NBH * NTOK * DH_) +
                             ((size_t)((b * HEADS_ + head) * NTOK + n)) * DH_ + dh] = f2b(val);
                } else if constexpr (EPI == EPI_RES) {
                    outf[(size_t)m * ldc + c] = resid[(size_t)m * ldc + c] + bias[c] + val;
                } else {  // EPI_GELU
                    const float xg = val + bias[c];
                    const float ge = 0.5f * xg * (1.0f + erff(xg * 0.70710678118f));
                    outb[(size_t)m * ldc + c] = f2b(ge);
                }
            }
        }
    }
}

// ---------------- fused LSA attention (flash-style) ----------------
// grid (16 q-tiles, 96 bh), block 256 (4 waves x 16 q-rows).
__launch_bounds__(256)
__global__ void attn_kernel(const u16* __restrict__ q, const u16* __restrict__ k,
                            const u16* __restrict__ v, const float* __restrict__ temp,
                            u16* __restrict__ o) {
    __shared__ u16 Ks[64 * 72];        // K tile row-major [kv][dh], padded
    __shared__ u16 Vt[64 * 72];        // V tile transposed [dh][kv], padded
    __shared__ u16 Ps[4 * 16 * 72];    // per-wave P tile [16 q][64 kv], padded
    const int t = threadIdx.x, lane = t & 63, w = t >> 6;
    const int bh = blockIdx.y, q0 = blockIdx.x * 64;
    const float scale = expf(temp[0]);
    const size_t base = (size_t)bh * (NTOK * DH_);

    // Q fragments (2 k-steps of 32) straight from global
    short8 aq[2];
#pragma unroll
    for (int s = 0; s < 2; s++)
        aq[s] = *reinterpret_cast<const short8*>(
            &q[base + (size_t)(q0 + w * 16 + (lane & 15)) * 64 + s * 32 + (lane >> 4) * 8]);

    float mrow[4], lrow[4];
#pragma unroll
    for (int r = 0; r < 4; r++) { mrow[r] = -3.0e38f; lrow[r] = 0.f; }
    f32x4 accO[4] = {};

    const int grow_base = q0 + w * 16 + (lane >> 4) * 4;

    for (int j0 = 0; j0 < NTOK; j0 += 64) {
        __syncthreads();
        // stage K row-major and V transposed
#pragma unroll
        for (int cc = 0; cc < 2; cc++) {
            const int idx = t + cc * 256;
            const int row = idx >> 3, ch = idx & 7;
            short8 k8 = *reinterpret_cast<const short8*>(&k[base + (size_t)(j0 + row) * 64 + ch * 8]);
            *reinterpret_cast<short8*>(&Ks[row * 72 + ch * 8]) = k8;
            short8 v8 = *reinterpret_cast<const short8*>(&v[base + (size_t)(j0 + row) * 64 + ch * 8]);
#pragma unroll
            for (int e = 0; e < 8; e++)
                Vt[(ch * 8 + e) * 72 + row] = (u16)v8[e];
        }
        __syncthreads();

        // S = Q K^T  (per wave: 16 q-rows x 64 kv-cols)
        f32x4 sf[4] = {};
#pragma unroll
        for (int c = 0; c < 4; c++)
#pragma unroll
            for (int s = 0; s < 2; s++) {
                short8 bk = *reinterpret_cast<const short8*>(
                    &Ks[(c * 16 + (lane & 15)) * 72 + s * 32 + (lane >> 4) * 8]);
                sf[c] = __builtin_amdgcn_mfma_f32_16x16x32_bf16(aq[s], bk, sf[c], 0, 0, 0);
            }

        // scale + LSA diagonal mask + online softmax
        float pv[4][4];
        float tmax[4];
#pragma unroll
        for (int r = 0; r < 4; r++) {
            const int grow = grow_base + r;
            float vmax = -3.0e38f;
#pragma unroll
            for (int c = 0; c < 4; c++) {
                float sv = sf[c][r] * scale;
                const int gcol = j0 + c * 16 + (lane & 15);
                if (gcol == grow) sv = -1.0e30f;
                pv[c][r] = sv;
                vmax = fmaxf(vmax, sv);
            }
#pragma unroll
            for (int m = 1; m < 16; m <<= 1) vmax = fmaxf(vmax, __shfl_xor(vmax, m));
            tmax[r] = vmax;
        }
#pragma unroll
        for (int r = 0; r < 4; r++) {
            const float mnew = fmaxf(mrow[r], tmax[r]);
            const float alpha = expf(mrow[r] - mnew);
            mrow[r] = mnew;
            float tsum = 0.f;
#pragma unroll
            for (int c = 0; c < 4; c++) {
                const float p = expf(pv[c][r] - mnew);
                pv[c][r] = p;
                tsum += p;
            }
#pragma unroll
            for (int m = 1; m < 16; m <<= 1) tsum += __shfl_xor(tsum, m);
            lrow[r] = lrow[r] * alpha + tsum;
#pragma unroll
            for (int g = 0; g < 4; g++) accO[g][r] *= alpha;
        }
        // write P (bf16) to per-wave LDS: layout [q-row 16][kv 64]
#pragma unroll
        for (int r = 0; r < 4; r++)
#pragma unroll
            for (int c = 0; c < 4; c++)
                Ps[w * 16 * 72 + ((lane >> 4) * 4 + r) * 72 + c * 16 + (lane & 15)] = f2b(pv[c][r]);

        // O += P V
#pragma unroll
        for (int s = 0; s < 2; s++) {
            short8 ap = *reinterpret_cast<const short8*>(
                &Ps[w * 16 * 72 + (lane & 15) * 72 + s * 32 + (lane >> 4) * 8]);
#pragma unroll
            for (int g = 0; g < 4; g++) {
                short8 bv = *reinterpret_cast<const short8*>(
                    &Vt[(g * 16 + (lane & 15)) * 72 + s * 32 + (lane >> 4) * 8]);
                accO[g] = __builtin_amdgcn_mfma_f32_16x16x32_bf16(ap, bv, accO[g], 0, 0, 0);
            }
        }
    }

    // write O (bf16) into token-major o[b*1024+n][head*64+dh]
    const int bidx = bh / HEADS_, head = bh % HEADS_;
#pragma unroll
    for (int g = 0; g < 4; g++)
#pragma unroll
        for (int r = 0; r < 4; r++) {
            const int n = q0 + w * 16 + (lane >> 4) * 4 + r;
            const int dh = g * 16 + (lane & 15);
            const float val = accO[g][r] / lrow[r];
            o[((size_t)(bidx * NTOK + n)) * DIM_ + head * DH_ + dh] = f2b(val);
        }
}

// ---------------- host ----------------
extern "C" void kernel_launch(void* const* d_in, const int* in_sizes, int n_in,
                              void* d_out, int out_size, void* d_ws, size_t ws_size,
                              hipStream_t stream) {
    const float* x_in  = (const float*)d_in[0];
    const float* ln1_g = (const float*)d_in[1];
    const float* ln1_b = (const float*)d_in[2];
    const float* qkv_w = (const float*)d_in[3];
    const float* temp  = (const float*)d_in[4];
    const float* out_w = (const float*)d_in[5];
    const float* out_b = (const float*)d_in[6];
    const float* ln2_g = (const float*)d_in[7];
    const float* ln2_b = (const float*)d_in[8];
    const float* ff_w1 = (const float*)d_in[9];
    const float* ff_b1 = (const float*)d_in[10];
    const float* ff_w2 = (const float*)d_in[11];
    const float* ff_b2 = (const float*)d_in[12];

    char* ws = (char*)d_ws;
    size_t off = 0;
    auto alloc = [&](size_t bytes) -> void* {
        void* p = ws + off;
        off += (bytes + 255) & ~(size_t)255;
        return p;
    };
    u16* wt_qkv = (u16*)alloc((size_t)DEPTH_ * 1152 * 384 * 2);
    u16* wt_out = (u16*)alloc((size_t)DEPTH_ * 384 * 384 * 2);
    u16* wt_ff1 = (u16*)alloc((size_t)DEPTH_ * 1536 * 384 * 2);
    u16* wt_ff2 = (u16*)alloc((size_t)DEPTH_ * 384 * 1536 * 2);
    u16* H      = (u16*)alloc((size_t)MTOT * DIM_ * 2);
    u16* QKV    = (u16*)alloc((size_t)MTOT * MLP_ * 2);  // union: qkv (37.7MB) / mlp mid (50.3MB)
    u16* MID    = QKV;

    float* X = (float*)d_out;  // residual stream lives in d_out (fp32)

    // init: X <- x
    hipMemcpyAsync(X, x_in, (size_t)MTOT * DIM_ * sizeof(float),
                   hipMemcpyDeviceToDevice, stream);

    // weight transpose+convert (once per call)
    transpose_w_kernel<<<dim3(6, 18, DEPTH_), 256, 0, stream>>>(qkv_w, wt_qkv, 384, 1152);
    transpose_w_kernel<<<dim3(6, 6, DEPTH_), 256, 0, stream>>>(out_w, wt_out, 384, 384);
    transpose_w_kernel<<<dim3(6, 24, DEPTH_), 256, 0, stream>>>(ff_w1, wt_ff1, 384, 1536);
    transpose_w_kernel<<<dim3(24, 6, DEPTH_), 256, 0, stream>>>(ff_w2, wt_ff2, 1536, 384);

    const size_t qkv_plane = (size_t)NBH * NTOK * DH_;  // 6291456 elems

    for (int layer = 0; layer < DEPTH_; layer++) {
        ln_kernel<<<4096, 256, 0, stream>>>(X, ln1_g + layer * DIM_, ln1_b + layer * DIM_, H);
        gemm_kernel<EPI_QKV><<<dim3(128, 9), 256, 0, stream>>>(
            H, wt_qkv + (size_t)layer * 1152 * 384, 384,
            nullptr, nullptr, nullptr, nullptr, 0, QKV);
        attn_kernel<<<dim3(16, 96), 256, 0, stream>>>(
            QKV, QKV + qkv_plane, QKV + 2 * qkv_plane, temp + layer, H);
        gemm_kernel<EPI_RES><<<dim3(128, 3), 256, 0, stream>>>(
            H, wt_out + (size_t)layer * 384 * 384, 384,
            out_b + layer * DIM_, X, X, nullptr, DIM_, nullptr);
        ln_kernel<<<4096, 256, 0, stream>>>(X, ln2_g + layer * DIM_, ln2_b + layer * DIM_, H);
        gemm_kernel<EPI_GELU><<<dim3(128, 12), 256, 0, stream>>>(
            H, wt_ff1 + (size_t)layer * 1536 * 384, 384,
            ff_b1 + layer * MLP_, nullptr, nullptr, MID, MLP_, nullptr);
        gemm_kernel<EPI_RES><<<dim3(128, 3), 256, 0, stream>>>(
            MID, wt_ff2 + (size_t)layer * 384 * 1536, 1536,
            ff_b2 + layer * DIM_, X, X, nullptr, DIM_, nullptr);
    }
}

// Round 4
// 1399.095 us; speedup vs baseline: 1.3256x; 1.3256x over previous
//
#include <hip/hip_runtime.h>
#include <hip/hip_bf16.h>
#include <math.h>

// ---------------- constants ----------------
#define B_     16
#define NTOK   1024
#define DIM_   384
#define DEPTH_ 6
#define HEADS_ 6
#define DH_    64
#define MLP_   1536
#define MTOT   (B_ * NTOK)    // 16384 tokens
#define NBH    (B_ * HEADS_)  // 96 batch-heads

typedef unsigned short u16;
typedef unsigned int u32;
typedef short short8 __attribute__((ext_vector_type(8)));
typedef float f32x4 __attribute__((ext_vector_type(4)));

static __device__ __forceinline__ u16 f2b(float f) {
    __hip_bfloat16 h = __float2bfloat16(f);
    return *reinterpret_cast<u16*>(&h);
}

// async global->LDS, 16B per lane; lds_ptr must be wave-uniform (HW adds lane*16)
#define GLOAD_LDS16(gp, lp)                                                     \
    __builtin_amdgcn_global_load_lds(                                           \
        (const __attribute__((address_space(1))) void*)(gp),                    \
        (__attribute__((address_space(3))) void*)(lp), 16, 0, 0)

// ---------------- weight transpose + bf16 convert ----------------
__launch_bounds__(256)
__global__ void transpose_w_kernel(const float* __restrict__ W, u16* __restrict__ WT,
                                   int K, int N) {
    const int layer = blockIdx.z;
    W  += (size_t)layer * K * N;
    WT += (size_t)layer * K * N;
    __shared__ u16 tile[64 * 72];
    const int t = threadIdx.x;
    const int k0 = blockIdx.x * 64, n0 = blockIdx.y * 64;
    const int row = t >> 2, cs = (t & 3) * 16;
    const float4* src = reinterpret_cast<const float4*>(W + (size_t)(k0 + row) * N + n0 + cs);
#pragma unroll
    for (int i = 0; i < 4; i++) {
        float4 f = src[i];
        tile[row * 72 + cs + i * 4 + 0] = f2b(f.x);
        tile[row * 72 + cs + i * 4 + 1] = f2b(f.y);
        tile[row * 72 + cs + i * 4 + 2] = f2b(f.z);
        tile[row * 72 + cs + i * 4 + 3] = f2b(f.w);
    }
    __syncthreads();
    const int nrow = row, ks = cs;
    u16 vals[16] __attribute__((aligned(16)));
#pragma unroll
    for (int e = 0; e < 16; e++) vals[e] = tile[(ks + e) * 72 + nrow];
    u16* dst = WT + (size_t)(n0 + nrow) * K + k0 + ks;
    *reinterpret_cast<short8*>(dst)     = *reinterpret_cast<short8*>(&vals[0]);
    *reinterpret_cast<short8*>(dst + 8) = *reinterpret_cast<short8*>(&vals[8]);
}

// ---------------- LayerNorm: fp32 x -> bf16 h ----------------
__launch_bounds__(256)
__global__ void ln_kernel(const float* __restrict__ x, const float* __restrict__ g,
                          const float* __restrict__ b, u16* __restrict__ h) {
    const int tok  = blockIdx.x * 4 + (threadIdx.x >> 6);
    const int lane = threadIdx.x & 63;
    const float* xr = x + (size_t)tok * DIM_;
    float v[6];
    float s = 0.f;
#pragma unroll
    for (int i = 0; i < 6; i++) { v[i] = xr[lane + i * 64]; s += v[i]; }
#pragma unroll
    for (int m = 1; m < 64; m <<= 1) s += __shfl_xor(s, m);
    const float mean = s * (1.f / 384.f);
    float qs = 0.f;
#pragma unroll
    for (int i = 0; i < 6; i++) { float d = v[i] - mean; qs += d * d; }
#pragma unroll
    for (int m = 1; m < 64; m <<= 1) qs += __shfl_xor(qs, m);
    const float inv = rsqrtf(qs * (1.f / 384.f) + 1e-5f);
    u16* hr = h + (size_t)tok * DIM_;
#pragma unroll
    for (int i = 0; i < 6; i++) {
        const int c = lane + i * 64;
        hr[c] = f2b((v[i] - mean) * inv * g[c] + b[c]);
    }
}

// ---------------- generic bf16 MFMA GEMM (global_load_lds staging) ----------------
// C[M,N] = A[M,K] @ B[K,N]; A row-major bf16, BT = B^T [N][K] bf16.
// 128x128 tile, 4 waves (2x2), 4x4 frags of 16x16x32, BK=32, linear LDS [128][32].
enum { EPI_QKV = 0, EPI_RES = 1, EPI_GELU = 2 };

template <int EPI>
__launch_bounds__(256)
__global__ void gemm_kernel(const u16* __restrict__ A, const u16* __restrict__ BT, int K,
                            const float* __restrict__ bias, const float* __restrict__ resid,
                            float* __restrict__ outf, u16* __restrict__ outb, int ldc,
                            u16* __restrict__ qkv_base) {
    __shared__ u16 As[128 * 32];
    __shared__ u16 Bs[128 * 32];
    const int t = threadIdx.x;
    const int lane = t & 63, w = t >> 6;
    const int wm = w >> 1, wn = w & 1;
    const int m0 = blockIdx.x * 128, n0 = blockIdx.y * 128;

    f32x4 acc[4][4] = {};

    // per-wave staging chunks: wave w loads 1KB chunks {2w, 2w+1} of each tile.
    // chunk c covers rows [c*16, c*16+16); lane -> row c*16 + (lane>>2), seg (lane&3)*8
    const int c0 = w * 2, c1 = w * 2 + 1;
    const int seg = (lane & 3) * 8;
    const u16* agp0 = A  + (size_t)(m0 + c0 * 16 + (lane >> 2)) * K + seg;
    const u16* agp1 = A  + (size_t)(m0 + c1 * 16 + (lane >> 2)) * K + seg;
    const u16* bgp0 = BT + (size_t)(n0 + c0 * 16 + (lane >> 2)) * K + seg;
    const u16* bgp1 = BT + (size_t)(n0 + c1 * 16 + (lane >> 2)) * K + seg;
    u16* asl0 = &As[c0 * 512];
    u16* asl1 = &As[c1 * 512];
    u16* bsl0 = &Bs[c0 * 512];
    u16* bsl1 = &Bs[c1 * 512];

    for (int kk = 0; kk < K; kk += 32) {
        __syncthreads();
        GLOAD_LDS16(agp0 + kk, asl0);
        GLOAD_LDS16(agp1 + kk, asl1);
        GLOAD_LDS16(bgp0 + kk, bsl0);
        GLOAD_LDS16(bgp1 + kk, bsl1);
        __syncthreads();
        short8 af[4], bf[4];
#pragma unroll
        for (int i = 0; i < 4; i++)
            af[i] = *reinterpret_cast<const short8*>(
                &As[(wm * 64 + i * 16 + (lane & 15)) * 32 + (lane >> 4) * 8]);
#pragma unroll
        for (int j = 0; j < 4; j++)
            bf[j] = *reinterpret_cast<const short8*>(
                &Bs[(wn * 64 + j * 16 + (lane & 15)) * 32 + (lane >> 4) * 8]);
#pragma unroll
        for (int i = 0; i < 4; i++)
#pragma unroll
            for (int j = 0; j < 4; j++)
                acc[i][j] = __builtin_amdgcn_mfma_f32_16x16x32_bf16(af[i], bf[j], acc[i][j], 0, 0, 0);
    }

    // epilogue: D layout col=lane&15, row=(lane>>4)*4+reg
    const int rbase = (lane >> 4) * 4;
    const int cb = lane & 15;
#pragma unroll
    for (int i = 0; i < 4; i++) {
#pragma unroll
        for (int j = 0; j < 4; j++) {
#pragma unroll
            for (int r = 0; r < 4; r++) {
                const int m = m0 + wm * 64 + i * 16 + rbase + r;
                const int c = n0 + wn * 64 + j * 16 + cb;
                const float val = acc[i][j][r];
                if constexpr (EPI == EPI_QKV) {
                    const int which = c / 384;
                    const int cc = c - which * 384;
                    const int head = cc >> 6, dh = cc & 63;
                    const int b = m >> 10, n = m & 1023;
                    qkv_base[(size_t)which * ((size_t)NBH * NTOK * DH_) +
                             ((size_t)((b * HEADS_ + head) * NTOK + n)) * DH_ + dh] = f2b(val);
                } else if constexpr (EPI == EPI_RES) {
                    outf[(size_t)m * ldc + c] = resid[(size_t)m * ldc + c] + bias[c] + val;
                } else {  // EPI_GELU
                    const float xg = val + bias[c];
                    const float ge = 0.5f * xg * (1.0f + erff(xg * 0.70710678118f));
                    outb[(size_t)m * ldc + c] = f2b(ge);
                }
            }
        }
    }
}

// ---------------- fused LSA attention, swapped-QK^T flash ----------------
// grid (96 bh, 16 q-tiles), block 256 (4 waves x 16 q-rows each).
// S^T = mfma(A=K, B=Q): lane owns full P row for q = lane&15 -> cheap softmax.
__launch_bounds__(256)
__global__ void attn_kernel(const u16* __restrict__ q, const u16* __restrict__ k,
                            const u16* __restrict__ v, const float* __restrict__ temp,
                            u16* __restrict__ o) {
    __shared__ u16 Ks[64 * 72];       // K tile row-major [kv][dh], pad 72
    __shared__ u16 Vt[64 * 88];       // V^T tile [dh][kv], stride 88 (16B-mult, conflict-free)
    __shared__ u16 Ps[4][16 * 80];    // per-wave P [q][kv], stride 80
    const int t = threadIdx.x, lane = t & 63, w = t >> 6;
    const int g8 = lane >> 4, qi = lane & 15;
    const int bh = blockIdx.x, q0 = blockIdx.y * 64;   // bh on x => same-XCD K/V reuse
    const float scale = __expf(temp[0]);
    const size_t base = (size_t)bh * (NTOK * DH_);

    // Q fragments (B-operand: n=q=qi, k=d)
    short8 bq[2];
#pragma unroll
    for (int s = 0; s < 2; s++)
        bq[s] = *reinterpret_cast<const short8*>(
            &q[base + (size_t)(q0 + w * 16 + qi) * 64 + s * 32 + g8 * 8]);

    float m_s = -3.0e38f, l_s = 0.f;   // softmax state for q = qi (uniform over g8)
    f32x4 accO[4] = {};
    const int qglob = q0 + w * 16 + qi;

    for (int j0 = 0; j0 < NTOK; j0 += 64) {
        __syncthreads();
        // stage K row-major: 64 rows x 128B, b128 writes
#pragma unroll
        for (int cc = 0; cc < 2; cc++) {
            const int idx = t + cc * 256;
            const int row = idx >> 3, ch = idx & 7;
            *reinterpret_cast<short8*>(&Ks[row * 72 + ch * 8]) =
                *reinterpret_cast<const short8*>(&k[base + (size_t)(j0 + row) * 64 + ch * 8]);
        }
        // stage V^T via register transpose: lane reads column `lane` of 8 rows
        // (each global read instr = 64 lanes x 2B = 128B coalesced row)
#pragma unroll
        for (int cc = 0; cc < 2; cc++) {
            const int kv0 = w * 16 + cc * 8;
            u16 tmp[8] __attribute__((aligned(16)));
#pragma unroll
            for (int j = 0; j < 8; j++)
                tmp[j] = v[base + (size_t)(j0 + kv0 + j) * 64 + lane];
            *reinterpret_cast<short8*>(&Vt[lane * 88 + kv0]) = *reinterpret_cast<short8*>(&tmp[0]);
        }
        __syncthreads();

        // S^T subtiles: per c, rows kv = c*16+m, cols q
        f32x4 sf[4] = {};
#pragma unroll
        for (int c = 0; c < 4; c++)
#pragma unroll
            for (int s = 0; s < 2; s++) {
                short8 af = *reinterpret_cast<const short8*>(
                    &Ks[(c * 16 + qi) * 72 + s * 32 + g8 * 8]);
                sf[c] = __builtin_amdgcn_mfma_f32_16x16x32_bf16(af, bq[s], sf[c], 0, 0, 0);
            }

        // scale + LSA mask + per-lane softmax over the 16 held kv values
        float p[4][4];
        float vmax = -3.0e38f;
#pragma unroll
        for (int c = 0; c < 4; c++)
#pragma unroll
            for (int r = 0; r < 4; r++) {
                float sv = sf[c][r] * scale;
                const int kvg = j0 + c * 16 + g8 * 4 + r;
                if (kvg == qglob) sv = -1.0e30f;
                p[c][r] = sv;
                vmax = fmaxf(vmax, sv);
            }
        vmax = fmaxf(vmax, __shfl_xor(vmax, 16));
        vmax = fmaxf(vmax, __shfl_xor(vmax, 32));
        const float mnew = fmaxf(m_s, vmax);
        const float alpha = __expf(m_s - mnew);
        m_s = mnew;
        float tsum = 0.f;
#pragma unroll
        for (int c = 0; c < 4; c++)
#pragma unroll
            for (int r = 0; r < 4; r++) {
                const float pe = __expf(p[c][r] - mnew);
                p[c][r] = pe;
                tsum += pe;
            }
        tsum += __shfl_xor(tsum, 16);
        tsum += __shfl_xor(tsum, 32);
        l_s = l_s * alpha + tsum;

        // rescale accO rows (row r holds q' = g8*4+r; its alpha lives in lane q')
#pragma unroll
        for (int r = 0; r < 4; r++) {
            const float a_r = __shfl(alpha, g8 * 4 + r, 64);
#pragma unroll
            for (int g = 0; g < 4; g++) accO[g][r] *= a_r;
        }

        // pack P -> per-wave LDS in A-fragment layout (vector b64 writes, no scatter)
#pragma unroll
        for (int c = 0; c < 4; c++) {
            u32 lo = (u32)f2b(p[c][0]) | ((u32)f2b(p[c][1]) << 16);
            u32 hi = (u32)f2b(p[c][2]) | ((u32)f2b(p[c][3]) << 16);
            uint2 pr; pr.x = lo; pr.y = hi;
            *reinterpret_cast<uint2*>(&Ps[w][qi * 80 + c * 16 + g8 * 4]) = pr;
        }

        // O += P V  (A = P from Ps, B-frag = V^T from Vt)
#pragma unroll
        for (int s = 0; s < 2; s++) {
            short8 ap = *reinterpret_cast<const short8*>(&Ps[w][qi * 80 + s * 32 + g8 * 8]);
#pragma unroll
            for (int g = 0; g < 4; g++) {
                short8 bv = *reinterpret_cast<const short8*>(
                    &Vt[(g * 16 + qi) * 88 + s * 32 + g8 * 8]);
                accO[g] = __builtin_amdgcn_mfma_f32_16x16x32_bf16(ap, bv, accO[g], 0, 0, 0);
            }
        }
    }

    // write O: lane row r holds q' = g8*4+r, dh = g*16+qi; l for q' is in lane q'
    const int bidx = bh / HEADS_, head = bh % HEADS_;
#pragma unroll
    for (int r = 0; r < 4; r++) {
        const float li = __shfl(l_s, g8 * 4 + r, 64);
        const float linv = 1.f / li;
        const int n = q0 + w * 16 + g8 * 4 + r;
#pragma unroll
        for (int g = 0; g < 4; g++) {
            const int dh = g * 16 + qi;
            o[((size_t)(bidx * NTOK + n)) * DIM_ + head * DH_ + dh] = f2b(accO[g][r] * linv);
        }
    }
}

// ---------------- host ----------------
extern "C" void kernel_launch(void* const* d_in, const int* in_sizes, int n_in,
                              void* d_out, int out_size, void* d_ws, size_t ws_size,
                              hipStream_t stream) {
    const float* x_in  = (const float*)d_in[0];
    const float* ln1_g = (const float*)d_in[1];
    const float* ln1_b = (const float*)d_in[2];
    const float* qkv_w = (const float*)d_in[3];
    const float* temp  = (const float*)d_in[4];
    const float* out_w = (const float*)d_in[5];
    const float* out_b = (const float*)d_in[6];
    const float* ln2_g = (const float*)d_in[7];
    const float* ln2_b = (const float*)d_in[8];
    const float* ff_w1 = (const float*)d_in[9];
    const float* ff_b1 = (const float*)d_in[10];
    const float* ff_w2 = (const float*)d_in[11];
    const float* ff_b2 = (const float*)d_in[12];

    char* ws = (char*)d_ws;
    size_t off = 0;
    auto alloc = [&](size_t bytes) -> void* {
        void* p = ws + off;
        off += (bytes + 255) & ~(size_t)255;
        return p;
    };
    u16* wt_qkv = (u16*)alloc((size_t)DEPTH_ * 1152 * 384 * 2);
    u16* wt_out = (u16*)alloc((size_t)DEPTH_ * 384 * 384 * 2);
    u16* wt_ff1 = (u16*)alloc((size_t)DEPTH_ * 1536 * 384 * 2);
    u16* wt_ff2 = (u16*)alloc((size_t)DEPTH_ * 384 * 1536 * 2);
    u16* H      = (u16*)alloc((size_t)MTOT * DIM_ * 2);
    u16* QKV    = (u16*)alloc((size_t)MTOT * MLP_ * 2);  // union: qkv (37.7MB) / mlp mid (50.3MB)
    u16* MID    = QKV;

    float* X = (float*)d_out;  // residual stream lives in d_out (fp32)

    hipMemcpyAsync(X, x_in, (size_t)MTOT * DIM_ * sizeof(float),
                   hipMemcpyDeviceToDevice, stream);

    transpose_w_kernel<<<dim3(6, 18, DEPTH_), 256, 0, stream>>>(qkv_w, wt_qkv, 384, 1152);
    transpose_w_kernel<<<dim3(6, 6, DEPTH_), 256, 0, stream>>>(out_w, wt_out, 384, 384);
    transpose_w_kernel<<<dim3(6, 24, DEPTH_), 256, 0, stream>>>(ff_w1, wt_ff1, 384, 1536);
    transpose_w_kernel<<<dim3(24, 6, DEPTH_), 256, 0, stream>>>(ff_w2, wt_ff2, 1536, 384);

    const size_t qkv_plane = (size_t)NBH * NTOK * DH_;  // 6291456 elems

    for (int layer = 0; layer < DEPTH_; layer++) {
        ln_kernel<<<4096, 256, 0, stream>>>(X, ln1_g + layer * DIM_, ln1_b + layer * DIM_, H);
        gemm_kernel<EPI_QKV><<<dim3(128, 9), 256, 0, stream>>>(
            H, wt_qkv + (size_t)layer * 1152 * 384, 384,
            nullptr, nullptr, nullptr, nullptr, 0, QKV);
        attn_kernel<<<dim3(96, 16), 256, 0, stream>>>(
            QKV, QKV + qkv_plane, QKV + 2 * qkv_plane, temp + layer, H);
        gemm_kernel<EPI_RES><<<dim3(128, 3), 256, 0, stream>>>(
            H, wt_out + (size_t)layer * 384 * 384, 384,
            out_b + layer * DIM_, X, X, nullptr, DIM_, nullptr);
        ln_kernel<<<4096, 256, 0, stream>>>(X, ln2_g + layer * DIM_, ln2_b + layer * DIM_, H);
        gemm_kernel<EPI_GELU><<<dim3(128, 12), 256, 0, stream>>>(
            H, wt_ff1 + (size_t)layer * 1536 * 384, 384,
            ff_b1 + layer * MLP_, nullptr, nullptr, MID, MLP_, nullptr);
        gemm_kernel<EPI_RES><<<dim3(128, 3), 256, 0, stream>>>(
            MID, wt_ff2 + (size_t)layer * 384 * 1536, 1536,
            ff_b2 + layer * DIM_, X, X, nullptr, DIM_, nullptr);
    }
}

// Round 5
// 1387.897 us; speedup vs baseline: 1.3363x; 1.0081x over previous
//
#include <hip/hip_runtime.h>
#include <hip/hip_bf16.h>
#include <math.h>

// ---------------- constants ----------------
#define B_     16
#define NTOK   1024
#define DIM_   384
#define DEPTH_ 6
#define HEADS_ 6
#define DH_    64
#define MLP_   1536
#define MTOT   (B_ * NTOK)    // 16384 tokens
#define NBH    (B_ * HEADS_)  // 96 batch-heads
#define QKV_PLANE ((size_t)NBH * NTOK * DH_)   // 6291456 elems per plane

typedef unsigned short u16;
typedef unsigned int u32;
typedef short short8 __attribute__((ext_vector_type(8)));
typedef float f32x4 __attribute__((ext_vector_type(4)));

static __device__ __forceinline__ u16 f2b(float f) {
    __hip_bfloat16 h = __float2bfloat16(f);
    return *reinterpret_cast<u16*>(&h);
}

// async global->LDS, 16B per lane; lds_ptr must be wave-uniform (HW adds lane*16)
#define GLOAD_LDS16(gp, lp)                                                     \
    __builtin_amdgcn_global_load_lds(                                           \
        (const __attribute__((address_space(1))) void*)(gp),                    \
        (__attribute__((address_space(3))) void*)(lp), 16, 0, 0)

// ---------------- weight transpose + bf16 convert ----------------
__launch_bounds__(256)
__global__ void transpose_w_kernel(const float* __restrict__ W, u16* __restrict__ WT,
                                   int K, int N) {
    const int layer = blockIdx.z;
    W  += (size_t)layer * K * N;
    WT += (size_t)layer * K * N;
    __shared__ u16 tile[64 * 72];
    const int t = threadIdx.x;
    const int k0 = blockIdx.x * 64, n0 = blockIdx.y * 64;
    const int row = t >> 2, cs = (t & 3) * 16;
    const float4* src = reinterpret_cast<const float4*>(W + (size_t)(k0 + row) * N + n0 + cs);
#pragma unroll
    for (int i = 0; i < 4; i++) {
        float4 f = src[i];
        tile[row * 72 + cs + i * 4 + 0] = f2b(f.x);
        tile[row * 72 + cs + i * 4 + 1] = f2b(f.y);
        tile[row * 72 + cs + i * 4 + 2] = f2b(f.z);
        tile[row * 72 + cs + i * 4 + 3] = f2b(f.w);
    }
    __syncthreads();
    const int nrow = row, ks = cs;
    u16 vals[16] __attribute__((aligned(16)));
#pragma unroll
    for (int e = 0; e < 16; e++) vals[e] = tile[(ks + e) * 72 + nrow];
    u16* dst = WT + (size_t)(n0 + nrow) * K + k0 + ks;
    *reinterpret_cast<short8*>(dst)     = *reinterpret_cast<short8*>(&vals[0]);
    *reinterpret_cast<short8*>(dst + 8) = *reinterpret_cast<short8*>(&vals[8]);
}

// ---------------- LayerNorm: fp32 x -> bf16 h ----------------
__launch_bounds__(256)
__global__ void ln_kernel(const float* __restrict__ x, const float* __restrict__ g,
                          const float* __restrict__ b, u16* __restrict__ h) {
    const int tok  = blockIdx.x * 4 + (threadIdx.x >> 6);
    const int lane = threadIdx.x & 63;
    const float* xr = x + (size_t)tok * DIM_;
    float v[6];
    float s = 0.f;
#pragma unroll
    for (int i = 0; i < 6; i++) { v[i] = xr[lane + i * 64]; s += v[i]; }
#pragma unroll
    for (int m = 1; m < 64; m <<= 1) s += __shfl_xor(s, m);
    const float mean = s * (1.f / 384.f);
    float qs = 0.f;
#pragma unroll
    for (int i = 0; i < 6; i++) { float d = v[i] - mean; qs += d * d; }
#pragma unroll
    for (int m = 1; m < 64; m <<= 1) qs += __shfl_xor(qs, m);
    const float inv = rsqrtf(qs * (1.f / 384.f) + 1e-5f);
    u16* hr = h + (size_t)tok * DIM_;
#pragma unroll
    for (int i = 0; i < 6; i++) {
        const int c = lane + i * 64;
        hr[c] = f2b((v[i] - mean) * inv * g[c] + b[c]);
    }
}

// ---------------- generic bf16 MFMA GEMM (global_load_lds staging) ----------------
// C[M,N] = A[M,K] @ B[K,N]; A row-major bf16, BT = B^T [N][K] bf16.
// 128x128 tile, 4 waves (2x2), 4x4 frags of 16x16x32, BK=32, linear LDS [128][32].
enum { EPI_QKV = 0, EPI_RES = 1, EPI_GELU = 2 };

template <int EPI>
__launch_bounds__(256)
__global__ void gemm_kernel(const u16* __restrict__ A, const u16* __restrict__ BT, int K,
                            const float* __restrict__ bias, const float* __restrict__ resid,
                            float* __restrict__ outf, u16* __restrict__ outb, int ldc,
                            u16* __restrict__ qkv_base) {
    __shared__ u16 As[128 * 32];
    __shared__ u16 Bs[128 * 32];
    const int t = threadIdx.x;
    const int lane = t & 63, w = t >> 6;
    const int wm = w >> 1, wn = w & 1;
    const int m0 = blockIdx.x * 128, n0 = blockIdx.y * 128;

    f32x4 acc[4][4] = {};

    const int c0 = w * 2, c1 = w * 2 + 1;
    const int seg = (lane & 3) * 8;
    const u16* agp0 = A  + (size_t)(m0 + c0 * 16 + (lane >> 2)) * K + seg;
    const u16* agp1 = A  + (size_t)(m0 + c1 * 16 + (lane >> 2)) * K + seg;
    const u16* bgp0 = BT + (size_t)(n0 + c0 * 16 + (lane >> 2)) * K + seg;
    const u16* bgp1 = BT + (size_t)(n0 + c1 * 16 + (lane >> 2)) * K + seg;
    u16* asl0 = &As[c0 * 512];
    u16* asl1 = &As[c1 * 512];
    u16* bsl0 = &Bs[c0 * 512];
    u16* bsl1 = &Bs[c1 * 512];

    for (int kk = 0; kk < K; kk += 32) {
        __syncthreads();
        GLOAD_LDS16(agp0 + kk, asl0);
        GLOAD_LDS16(agp1 + kk, asl1);
        GLOAD_LDS16(bgp0 + kk, bsl0);
        GLOAD_LDS16(bgp1 + kk, bsl1);
        __syncthreads();
        short8 af[4], bf[4];
#pragma unroll
        for (int i = 0; i < 4; i++)
            af[i] = *reinterpret_cast<const short8*>(
                &As[(wm * 64 + i * 16 + (lane & 15)) * 32 + (lane >> 4) * 8]);
#pragma unroll
        for (int j = 0; j < 4; j++)
            bf[j] = *reinterpret_cast<const short8*>(
                &Bs[(wn * 64 + j * 16 + (lane & 15)) * 32 + (lane >> 4) * 8]);
#pragma unroll
        for (int i = 0; i < 4; i++)
#pragma unroll
            for (int j = 0; j < 4; j++)
                acc[i][j] = __builtin_amdgcn_mfma_f32_16x16x32_bf16(af[i], bf[j], acc[i][j], 0, 0, 0);
    }

    // epilogue: D layout col=lane&15, row=(lane>>4)*4+reg
    const int rbase = (lane >> 4) * 4;
    const int cb = lane & 15;
#pragma unroll
    for (int i = 0; i < 4; i++) {
#pragma unroll
        for (int j = 0; j < 4; j++) {
            if constexpr (EPI == EPI_QKV) {
                // Q plane: [bh][n][dh] linear.
                // K plane: [bh][n][dh] with 16B chunks XOR-swizzled by (n&7).
                // V plane: [bh][dh][n] (transposed) with 16B chunks XOR-swizzled by (dh&7).
                const int c = n0 + wn * 64 + j * 16 + cb;
                const int which = c / 384;
                const int cc = c - which * 384;
                const int head = cc >> 6, dh = cc & 63;
                const int nb = m0 + wm * 64 + i * 16 + rbase;   // 4 consecutive tokens
                const int b = nb >> 10, nt = nb & 1023;
                const size_t bh = (size_t)(b * HEADS_ + head);
                if (which == 2) {
                    u16 pk[4] __attribute__((aligned(8)));
#pragma unroll
                    for (int r = 0; r < 4; r++) pk[r] = f2b(acc[i][j][r]);
                    const int nsw = (nt & ~63) | ((((nt >> 3) & 7) ^ (dh & 7)) << 3) | (nt & 7);
                    *reinterpret_cast<uint2*>(
                        &qkv_base[2 * QKV_PLANE + bh * 65536 + (size_t)dh * 1024 + nsw]) =
                        *reinterpret_cast<uint2*>(pk);
                } else if (which == 1) {
#pragma unroll
                    for (int r = 0; r < 4; r++) {
                        const int n = nt + r;
                        const int dsw = (((dh >> 3) ^ (n & 7)) << 3) | (dh & 7);
                        qkv_base[QKV_PLANE + bh * 65536 + (size_t)n * 64 + dsw] =
                            f2b(acc[i][j][r]);
                    }
                } else {
#pragma unroll
                    for (int r = 0; r < 4; r++)
                        qkv_base[bh * 65536 + (size_t)(nt + r) * 64 + dh] = f2b(acc[i][j][r]);
                }
            } else {
#pragma unroll
                for (int r = 0; r < 4; r++) {
                    const int m = m0 + wm * 64 + i * 16 + rbase + r;
                    const int c = n0 + wn * 64 + j * 16 + cb;
                    const float val = acc[i][j][r];
                    if constexpr (EPI == EPI_RES) {
                        outf[(size_t)m * ldc + c] = resid[(size_t)m * ldc + c] + bias[c] + val;
                    } else {  // EPI_GELU
                        const float xg = val + bias[c];
                        const float ge = 0.5f * xg * (1.0f + erff(xg * 0.70710678118f));
                        outb[(size_t)m * ldc + c] = f2b(ge);
                    }
                }
            }
        }
    }
}

// ---------------- fused LSA attention, swapped-QK^T flash, gload_lds staging ------
// grid (96 bh, 16 q-tiles), block 256 (4 waves x 16 q-rows each).
// K' and V^T' planes are chunk-swizzled by the QKV epilogue (rule #21 both-sides).
__launch_bounds__(256)
__global__ void attn_kernel(const u16* __restrict__ q, const u16* __restrict__ k,
                            const u16* __restrict__ v, const float* __restrict__ temp,
                            u16* __restrict__ o) {
    __shared__ u16 Kt[64 * 64];       // [kv][dh] linear, content chunk-swizzled by kv&7
    __shared__ u16 Vt[64 * 64];       // [dh][kv] linear, content chunk-swizzled by dh&7
    __shared__ u16 Ps[4][16 * 80];    // per-wave P [q][kv], stride 80
    const int t = threadIdx.x, lane = t & 63, w = t >> 6;
    const int g8 = lane >> 4, qi = lane & 15;
    const int bh = blockIdx.x, q0 = blockIdx.y * 64;
    const float scale2 = __expf(temp[0]) * 1.4426950408889634f;  // log2-domain scale
    const size_t base = (size_t)bh * (NTOK * DH_);

    // Q fragments (B-operand: n=q=qi, k=d)
    short8 bq[2];
#pragma unroll
    for (int s = 0; s < 2; s++)
        bq[s] = *reinterpret_cast<const short8*>(
            &q[base + (size_t)(q0 + w * 16 + qi) * 64 + s * 32 + g8 * 8]);

    float m_s = -3.0e38f, l_s = 0.f;   // log2-domain softmax state for q = qi
    f32x4 accO[4] = {};
    const int qglob = q0 + w * 16 + qi;

    // staging source/dest (wave-uniform LDS base, per-lane global)
    const int srow = w * 8 + (lane >> 3);
    const int schunk = (lane & 7) * 8;
    const u16* kg0 = k + base + (size_t)srow * 64 + schunk;     // +j0*64, +32*64 for round 1
    const u16* vg0 = v + base + (size_t)srow * 1024 + schunk;   // +j0,    +32*1024
    u16* klds = &Kt[w * 512];                                   // +2048 for round 1
    u16* vlds = &Vt[w * 512];

    for (int j0 = 0; j0 < NTOK; j0 += 64) {
        __syncthreads();
        GLOAD_LDS16(kg0 + (size_t)j0 * 64,            klds);
        GLOAD_LDS16(kg0 + (size_t)j0 * 64 + 32 * 64,  klds + 2048);
        GLOAD_LDS16(vg0 + j0,                         vlds);
        GLOAD_LDS16(vg0 + j0 + 32 * 1024,             vlds + 2048);
        __syncthreads();

        // S^T subtiles: A = K rows (kv = c*16+qi), B = Q
        f32x4 sf[4] = {};
#pragma unroll
        for (int c = 0; c < 4; c++) {
            const int krow = c * 16 + qi;
#pragma unroll
            for (int s = 0; s < 2; s++) {
                short8 af = *reinterpret_cast<const short8*>(
                    &Kt[krow * 64 + (((s * 4 + g8) ^ (krow & 7)) << 3)]);
                sf[c] = __builtin_amdgcn_mfma_f32_16x16x32_bf16(af, bq[s], sf[c], 0, 0, 0);
            }
        }

        // scale (+ LSA diagonal mask, block-uniform branch)
        float p[4][4];
        float vmax = -3.0e38f;
        if (j0 == q0) {
#pragma unroll
            for (int c = 0; c < 4; c++)
#pragma unroll
                for (int r = 0; r < 4; r++) {
                    float sv = sf[c][r] * scale2;
                    if (j0 + c * 16 + g8 * 4 + r == qglob) sv = -3.0e37f;
                    p[c][r] = sv;
                    vmax = fmaxf(vmax, sv);
                }
        } else {
#pragma unroll
            for (int c = 0; c < 4; c++)
#pragma unroll
                for (int r = 0; r < 4; r++) {
                    const float sv = sf[c][r] * scale2;
                    p[c][r] = sv;
                    vmax = fmaxf(vmax, sv);
                }
        }
        vmax = fmaxf(vmax, __shfl_xor(vmax, 16));
        vmax = fmaxf(vmax, __shfl_xor(vmax, 32));

        // defer-max: only rescale when max grew past threshold (2^11 headroom, fp32-safe)
        if (!__all(vmax - m_s <= 11.0f)) {
            const float mnew = fmaxf(m_s, vmax);
            const float alpha = exp2f(m_s - mnew);
            m_s = mnew;
            l_s *= alpha;
#pragma unroll
            for (int r = 0; r < 4; r++) {
                const float a_r = __shfl(alpha, g8 * 4 + r, 64);
#pragma unroll
                for (int g = 0; g < 4; g++) accO[g][r] *= a_r;
            }
        }

        float tsum = 0.f;
#pragma unroll
        for (int c = 0; c < 4; c++)
#pragma unroll
            for (int r = 0; r < 4; r++) {
                const float pe = exp2f(p[c][r] - m_s);
                p[c][r] = pe;
                tsum += pe;
            }
        tsum += __shfl_xor(tsum, 16);
        tsum += __shfl_xor(tsum, 32);
        l_s += tsum;

        // pack P -> per-wave LDS in A-fragment layout (vector b64 writes)
#pragma unroll
        for (int c = 0; c < 4; c++) {
            u32 lo = (u32)f2b(p[c][0]) | ((u32)f2b(p[c][1]) << 16);
            u32 hi = (u32)f2b(p[c][2]) | ((u32)f2b(p[c][3]) << 16);
            uint2 pr; pr.x = lo; pr.y = hi;
            *reinterpret_cast<uint2*>(&Ps[w][qi * 80 + c * 16 + g8 * 4]) = pr;
        }

        // O += P V  (A = P, B-frag = V^T rows with XOR-swizzled chunks)
#pragma unroll
        for (int s = 0; s < 2; s++) {
            short8 ap = *reinterpret_cast<const short8*>(&Ps[w][qi * 80 + s * 32 + g8 * 8]);
#pragma unroll
            for (int g = 0; g < 4; g++) {
                const int vrow = g * 16 + qi;
                short8 bv = *reinterpret_cast<const short8*>(
                    &Vt[vrow * 64 + (((s * 4 + g8) ^ (vrow & 7)) << 3)]);
                accO[g] = __builtin_amdgcn_mfma_f32_16x16x32_bf16(ap, bv, accO[g], 0, 0, 0);
            }
        }
    }

    // write O: lane row r holds q' = g8*4+r, dh = g*16+qi; l for q' is in lane q'
    const int bidx = bh / HEADS_, head = bh % HEADS_;
#pragma unroll
    for (int r = 0; r < 4; r++) {
        const float li = __shfl(l_s, g8 * 4 + r, 64);
        const float linv = 1.f / li;
        const int n = q0 + w * 16 + g8 * 4 + r;
#pragma unroll
        for (int g = 0; g < 4; g++) {
            const int dh = g * 16 + qi;
            o[((size_t)(bidx * NTOK + n)) * DIM_ + head * DH_ + dh] = f2b(accO[g][r] * linv);
        }
    }
}

// ---------------- host ----------------
extern "C" void kernel_launch(void* const* d_in, const int* in_sizes, int n_in,
                              void* d_out, int out_size, void* d_ws, size_t ws_size,
                              hipStream_t stream) {
    const float* x_in  = (const float*)d_in[0];
    const float* ln1_g = (const float*)d_in[1];
    const float* ln1_b = (const float*)d_in[2];
    const float* qkv_w = (const float*)d_in[3];
    const float* temp  = (const float*)d_in[4];
    const float* out_w = (const float*)d_in[5];
    const float* out_b = (const float*)d_in[6];
    const float* ln2_g = (const float*)d_in[7];
    const float* ln2_b = (const float*)d_in[8];
    const float* ff_w1 = (const float*)d_in[9];
    const float* ff_b1 = (const float*)d_in[10];
    const float* ff_w2 = (const float*)d_in[11];
    const float* ff_b2 = (const float*)d_in[12];

    char* ws = (char*)d_ws;
    size_t off = 0;
    auto alloc = [&](size_t bytes) -> void* {
        void* p = ws + off;
        off += (bytes + 255) & ~(size_t)255;
        return p;
    };
    u16* wt_qkv = (u16*)alloc((size_t)DEPTH_ * 1152 * 384 * 2);
    u16* wt_out = (u16*)alloc((size_t)DEPTH_ * 384 * 384 * 2);
    u16* wt_ff1 = (u16*)alloc((size_t)DEPTH_ * 1536 * 384 * 2);
    u16* wt_ff2 = (u16*)alloc((size_t)DEPTH_ * 384 * 1536 * 2);
    u16* H      = (u16*)alloc((size_t)MTOT * DIM_ * 2);
    u16* QKV    = (u16*)alloc((size_t)MTOT * MLP_ * 2);  // union: qkv (37.7MB) / mlp mid (50.3MB)
    u16* MID    = QKV;

    float* X = (float*)d_out;  // residual stream lives in d_out (fp32)

    hipMemcpyAsync(X, x_in, (size_t)MTOT * DIM_ * sizeof(float),
                   hipMemcpyDeviceToDevice, stream);

    transpose_w_kernel<<<dim3(6, 18, DEPTH_), 256, 0, stream>>>(qkv_w, wt_qkv, 384, 1152);
    transpose_w_kernel<<<dim3(6, 6, DEPTH_), 256, 0, stream>>>(out_w, wt_out, 384, 384);
    transpose_w_kernel<<<dim3(6, 24, DEPTH_), 256, 0, stream>>>(ff_w1, wt_ff1, 384, 1536);
    transpose_w_kernel<<<dim3(24, 6, DEPTH_), 256, 0, stream>>>(ff_w2, wt_ff2, 1536, 384);

    for (int layer = 0; layer < DEPTH_; layer++) {
        ln_kernel<<<4096, 256, 0, stream>>>(X, ln1_g + layer * DIM_, ln1_b + layer * DIM_, H);
        gemm_kernel<EPI_QKV><<<dim3(128, 9), 256, 0, stream>>>(
            H, wt_qkv + (size_t)layer * 1152 * 384, 384,
            nullptr, nullptr, nullptr, nullptr, 0, QKV);
        attn_kernel<<<dim3(96, 16), 256, 0, stream>>>(
            QKV, QKV + QKV_PLANE, QKV + 2 * QKV_PLANE, temp + layer, H);
        gemm_kernel<EPI_RES><<<dim3(128, 3), 256, 0, stream>>>(
            H, wt_out + (size_t)layer * 384 * 384, 384,
            out_b + layer * DIM_, X, X, nullptr, DIM_, nullptr);
        ln_kernel<<<4096, 256, 0, stream>>>(X, ln2_g + layer * DIM_, ln2_b + layer * DIM_, H);
        gemm_kernel<EPI_GELU><<<dim3(128, 12), 256, 0, stream>>>(
            H, wt_ff1 + (size_t)layer * 1536 * 384, 384,
            ff_b1 + layer * MLP_, nullptr, nullptr, MID, MLP_, nullptr);
        gemm_kernel<EPI_RES><<<dim3(128, 3), 256, 0, stream>>>(
            MID, wt_ff2 + (size_t)layer * 384 * 1536, 1536,
            ff_b2 + layer * DIM_, X, X, nullptr, DIM_, nullptr);
    }
}

// Round 6
// 1370.809 us; speedup vs baseline: 1.3529x; 1.0125x over previous
//
#include <hip/hip_runtime.h>
#include <hip/hip_bf16.h>
#include <math.h>

// ---------------- constants ----------------
#define B_     16
#define NTOK   1024
#define DIM_   384
#define DEPTH_ 6
#define HEADS_ 6
#define DH_    64
#define MLP_   1536
#define MTOT   (B_ * NTOK)    // 16384 tokens
#define NBH    (B_ * HEADS_)  // 96 batch-heads
#define QKV_PLANE ((size_t)NBH * NTOK * DH_)   // 6291456 elems per plane

typedef unsigned short u16;
typedef unsigned int u32;
typedef short short8 __attribute__((ext_vector_type(8)));
typedef float f32x4 __attribute__((ext_vector_type(4)));

static __device__ __forceinline__ u16 f2b(float f) {
    __hip_bfloat16 h = __float2bfloat16(f);
    return *reinterpret_cast<u16*>(&h);
}

// async global->LDS, 16B per lane; lds_ptr must be wave-uniform (HW adds lane*16)
#define GLOAD_LDS16(gp, lp)                                                     \
    __builtin_amdgcn_global_load_lds(                                           \
        (const __attribute__((address_space(1))) void*)(gp),                    \
        (__attribute__((address_space(3))) void*)(lp), 16, 0, 0)

#define WAIT_VM(N)                                                              \
    do { asm volatile("s_waitcnt vmcnt(" #N ")" ::: "memory");                  \
         __builtin_amdgcn_sched_barrier(0); } while (0)
#define WAIT_LGKM0()                                                            \
    do { asm volatile("s_waitcnt lgkmcnt(0)" ::: "memory");                     \
         __builtin_amdgcn_sched_barrier(0); } while (0)

// ---------------- weight transpose + bf16 convert ----------------
__launch_bounds__(256)
__global__ void transpose_w_kernel(const float* __restrict__ W, u16* __restrict__ WT,
                                   int K, int N) {
    const int layer = blockIdx.z;
    W  += (size_t)layer * K * N;
    WT += (size_t)layer * K * N;
    __shared__ u16 tile[64 * 72];
    const int t = threadIdx.x;
    const int k0 = blockIdx.x * 64, n0 = blockIdx.y * 64;
    const int row = t >> 2, cs = (t & 3) * 16;
    const float4* src = reinterpret_cast<const float4*>(W + (size_t)(k0 + row) * N + n0 + cs);
#pragma unroll
    for (int i = 0; i < 4; i++) {
        float4 f = src[i];
        tile[row * 72 + cs + i * 4 + 0] = f2b(f.x);
        tile[row * 72 + cs + i * 4 + 1] = f2b(f.y);
        tile[row * 72 + cs + i * 4 + 2] = f2b(f.z);
        tile[row * 72 + cs + i * 4 + 3] = f2b(f.w);
    }
    __syncthreads();
    const int nrow = row, ks = cs;
    u16 vals[16] __attribute__((aligned(16)));
#pragma unroll
    for (int e = 0; e < 16; e++) vals[e] = tile[(ks + e) * 72 + nrow];
    u16* dst = WT + (size_t)(n0 + nrow) * K + k0 + ks;
    *reinterpret_cast<short8*>(dst)     = *reinterpret_cast<short8*>(&vals[0]);
    *reinterpret_cast<short8*>(dst + 8) = *reinterpret_cast<short8*>(&vals[8]);
}

// ---------------- LayerNorm: fp32 x -> bf16 h ----------------
__launch_bounds__(256)
__global__ void ln_kernel(const float* __restrict__ x, const float* __restrict__ g,
                          const float* __restrict__ b, u16* __restrict__ h) {
    const int tok  = blockIdx.x * 4 + (threadIdx.x >> 6);
    const int lane = threadIdx.x & 63;
    const float* xr = x + (size_t)tok * DIM_;
    float v[6];
    float s = 0.f;
#pragma unroll
    for (int i = 0; i < 6; i++) { v[i] = xr[lane + i * 64]; s += v[i]; }
#pragma unroll
    for (int m = 1; m < 64; m <<= 1) s += __shfl_xor(s, m);
    const float mean = s * (1.f / 384.f);
    float qs = 0.f;
#pragma unroll
    for (int i = 0; i < 6; i++) { float d = v[i] - mean; qs += d * d; }
#pragma unroll
    for (int m = 1; m < 64; m <<= 1) qs += __shfl_xor(qs, m);
    const float inv = rsqrtf(qs * (1.f / 384.f) + 1e-5f);
    u16* hr = h + (size_t)tok * DIM_;
#pragma unroll
    for (int i = 0; i < 6; i++) {
        const int c = lane + i * 64;
        hr[c] = f2b((v[i] - mean) * inv * g[c] + b[c]);
    }
}

// ---------------- generic bf16 MFMA GEMM, 3-buffer counted-vmcnt pipeline -------
// C[M,N] = A[M,K] @ B[K,N]; A row-major bf16, BT = B^T [N][K] bf16.
// 128x128 tile, 4 waves (2x2), 4x4 frags of 16x16x32, BK=32, linear LDS [128][32].
// Iter t: issue loads for t+2 (ring buf), wait vmcnt(8) (t's loads only), raw
// barrier (t+1/t+2 loads stay in flight across it), MFMA from buf t.
enum { EPI_QKV = 0, EPI_RES = 1, EPI_GELU = 2 };

template <int EPI>
__launch_bounds__(256)
__global__ void gemm_kernel(const u16* __restrict__ A, const u16* __restrict__ BT, int K,
                            const float* __restrict__ bias, const float* __restrict__ resid,
                            float* __restrict__ outf, u16* __restrict__ outb, int ldc,
                            u16* __restrict__ qkv_base) {
    __shared__ u16 As[3][4096];
    __shared__ u16 Bs[3][4096];
    const int t = threadIdx.x;
    const int lane = t & 63, w = t >> 6;
    const int wm = w >> 1, wn = w & 1;
    const int m0 = blockIdx.x * 128, n0 = blockIdx.y * 128;

    f32x4 acc[4][4] = {};

    const int c0p = w * 1024, c1p = w * 1024 + 512;   // elem offsets of wave's 2 chunks
    const int seg = (lane & 3) * 8;
    const u16* agp0 = A  + (size_t)(m0 + (w * 2 + 0) * 16 + (lane >> 2)) * K + seg;
    const u16* agp1 = A  + (size_t)(m0 + (w * 2 + 1) * 16 + (lane >> 2)) * K + seg;
    const u16* bgp0 = BT + (size_t)(n0 + (w * 2 + 0) * 16 + (lane >> 2)) * K + seg;
    const u16* bgp1 = BT + (size_t)(n0 + (w * 2 + 1) * 16 + (lane >> 2)) * K + seg;

    const int T = K >> 5;
    // prologue: t=0 -> buf0, t=1 -> buf1
    GLOAD_LDS16(agp0,      &As[0][c0p]);
    GLOAD_LDS16(agp1,      &As[0][c1p]);
    GLOAD_LDS16(bgp0,      &Bs[0][c0p]);
    GLOAD_LDS16(bgp1,      &Bs[0][c1p]);
    GLOAD_LDS16(agp0 + 32, &As[1][c0p]);
    GLOAD_LDS16(agp1 + 32, &As[1][c1p]);
    GLOAD_LDS16(bgp0 + 32, &Bs[1][c0p]);
    GLOAD_LDS16(bgp1 + 32, &Bs[1][c1p]);

    int b0 = 0, b1 = 1, b2 = 2;
    for (int tt = 0; tt < T; ++tt) {
        if (tt + 2 < T) {
            const int kk = (tt + 2) << 5;
            GLOAD_LDS16(agp0 + kk, &As[b2][c0p]);
            GLOAD_LDS16(agp1 + kk, &As[b2][c1p]);
            GLOAD_LDS16(bgp0 + kk, &Bs[b2][c0p]);
            GLOAD_LDS16(bgp1 + kk, &Bs[b2][c1p]);
            WAIT_VM(8);
        } else if (tt + 1 < T) {
            WAIT_VM(4);
        } else {
            WAIT_VM(0);
        }
        __builtin_amdgcn_s_barrier();
        short8 af[4], bf[4];
#pragma unroll
        for (int i = 0; i < 4; i++)
            af[i] = *reinterpret_cast<const short8*>(
                &As[b0][(wm * 64 + i * 16 + (lane & 15)) * 32 + (lane >> 4) * 8]);
#pragma unroll
        for (int j = 0; j < 4; j++)
            bf[j] = *reinterpret_cast<const short8*>(
                &Bs[b0][(wn * 64 + j * 16 + (lane & 15)) * 32 + (lane >> 4) * 8]);
#pragma unroll
        for (int i = 0; i < 4; i++)
#pragma unroll
            for (int j = 0; j < 4; j++)
                acc[i][j] = __builtin_amdgcn_mfma_f32_16x16x32_bf16(af[i], bf[j], acc[i][j], 0, 0, 0);
        WAIT_LGKM0();
        __builtin_amdgcn_s_barrier();
        const int tmp = b0; b0 = b1; b1 = b2; b2 = tmp;
    }

    // epilogue: D layout col=lane&15, row=(lane>>4)*4+reg
    const int rbase = (lane >> 4) * 4;
    const int cb = lane & 15;
#pragma unroll
    for (int i = 0; i < 4; i++) {
#pragma unroll
        for (int j = 0; j < 4; j++) {
            if constexpr (EPI == EPI_QKV) {
                // Q plane: [bh][n][dh] linear.
                // K plane: [bh][n][dh] with 16B chunks XOR-swizzled by (n&7).
                // V plane: [bh][dh][n] (transposed) with 16B chunks XOR-swizzled by (dh&7).
                const int c = n0 + wn * 64 + j * 16 + cb;
                const int which = c / 384;
                const int cc = c - which * 384;
                const int head = cc >> 6, dh = cc & 63;
                const int nb = m0 + wm * 64 + i * 16 + rbase;   // 4 consecutive tokens
                const int b = nb >> 10, nt = nb & 1023;
                const size_t bh = (size_t)(b * HEADS_ + head);
                if (which == 2) {
                    u16 pk[4] __attribute__((aligned(8)));
#pragma unroll
                    for (int r = 0; r < 4; r++) pk[r] = f2b(acc[i][j][r]);
                    const int nsw = (nt & ~63) | ((((nt >> 3) & 7) ^ (dh & 7)) << 3) | (nt & 7);
                    *reinterpret_cast<uint2*>(
                        &qkv_base[2 * QKV_PLANE + bh * 65536 + (size_t)dh * 1024 + nsw]) =
                        *reinterpret_cast<uint2*>(pk);
                } else if (which == 1) {
#pragma unroll
                    for (int r = 0; r < 4; r++) {
                        const int n = nt + r;
                        const int dsw = (((dh >> 3) ^ (n & 7)) << 3) | (dh & 7);
                        qkv_base[QKV_PLANE + bh * 65536 + (size_t)n * 64 + dsw] =
                            f2b(acc[i][j][r]);
                    }
                } else {
#pragma unroll
                    for (int r = 0; r < 4; r++)
                        qkv_base[bh * 65536 + (size_t)(nt + r) * 64 + dh] = f2b(acc[i][j][r]);
                }
            } else {
#pragma unroll
                for (int r = 0; r < 4; r++) {
                    const int m = m0 + wm * 64 + i * 16 + rbase + r;
                    const int c = n0 + wn * 64 + j * 16 + cb;
                    const float val = acc[i][j][r];
                    if constexpr (EPI == EPI_RES) {
                        outf[(size_t)m * ldc + c] = resid[(size_t)m * ldc + c] + bias[c] + val;
                    } else {  // EPI_GELU
                        const float xg = val + bias[c];
                        const float ge = 0.5f * xg * (1.0f + erff(xg * 0.70710678118f));
                        outb[(size_t)m * ldc + c] = f2b(ge);
                    }
                }
            }
        }
    }
}

// ---------------- fused LSA attention, swapped-QK^T flash, dbuf counted-vmcnt ----
// grid (96 bh, 16 q-tiles), block 256 (4 waves x 16 q-rows each).
// K' and V^T' planes are chunk-swizzled by the QKV epilogue (rule #21 both-sides).
__launch_bounds__(256)
__global__ void attn_kernel(const u16* __restrict__ q, const u16* __restrict__ k,
                            const u16* __restrict__ v, const float* __restrict__ temp,
                            u16* __restrict__ o) {
    __shared__ u16 Kt[2][4096];       // [kv][dh] linear, content chunk-swizzled by kv&7
    __shared__ u16 Vt[2][4096];       // [dh][kv] linear, content chunk-swizzled by dh&7
    __shared__ u16 Ps[4][16 * 80];    // per-wave P [q][kv], stride 80
    const int t = threadIdx.x, lane = t & 63, w = t >> 6;
    const int g8 = lane >> 4, qi = lane & 15;
    const int bh = blockIdx.x, q0 = blockIdx.y * 64;
    const float scale2 = __expf(temp[0]) * 1.4426950408889634f;  // log2-domain scale
    const size_t base = (size_t)bh * (NTOK * DH_);

    // Q fragments (B-operand: n=q=qi, k=d)
    short8 bq[2];
#pragma unroll
    for (int s = 0; s < 2; s++)
        bq[s] = *reinterpret_cast<const short8*>(
            &q[base + (size_t)(q0 + w * 16 + qi) * 64 + s * 32 + g8 * 8]);

    float m_s = -3.0e38f, l_s = 0.f;   // log2-domain softmax state for q = qi
    f32x4 accO[4] = {};
    const int qglob = q0 + w * 16 + qi;

    // staging source/dest (wave-uniform LDS base, per-lane global)
    const int srow = w * 8 + (lane >> 3);
    const int schunk = (lane & 7) * 8;
    const u16* kg0 = k + base + (size_t)srow * 64 + schunk;
    const u16* vg0 = v + base + (size_t)srow * 1024 + schunk;
    const int wp = w * 512;

    // prologue: stage tile 0 into buf 0
    GLOAD_LDS16(kg0,             &Kt[0][wp]);
    GLOAD_LDS16(kg0 + 32 * 64,   &Kt[0][wp + 2048]);
    GLOAD_LDS16(vg0,             &Vt[0][wp]);
    GLOAD_LDS16(vg0 + 32 * 1024, &Vt[0][wp + 2048]);

    int cur = 0;
    for (int jt = 0; jt < 16; ++jt) {
        if (jt + 1 < 16) {
            const size_t jn = (size_t)(jt + 1) * 64;
            GLOAD_LDS16(kg0 + jn * 64,            &Kt[cur ^ 1][wp]);
            GLOAD_LDS16(kg0 + jn * 64 + 32 * 64,  &Kt[cur ^ 1][wp + 2048]);
            GLOAD_LDS16(vg0 + jn,                 &Vt[cur ^ 1][wp]);
            GLOAD_LDS16(vg0 + jn + 32 * 1024,     &Vt[cur ^ 1][wp + 2048]);
            WAIT_VM(4);
        } else {
            WAIT_VM(0);
        }
        __builtin_amdgcn_s_barrier();

        // S^T subtiles: A = K rows (kv = c*16+qi), B = Q
        f32x4 sf[4] = {};
#pragma unroll
        for (int c = 0; c < 4; c++) {
            const int krow = c * 16 + qi;
#pragma unroll
            for (int s = 0; s < 2; s++) {
                short8 af = *reinterpret_cast<const short8*>(
                    &Kt[cur][krow * 64 + (((s * 4 + g8) ^ (krow & 7)) << 3)]);
                sf[c] = __builtin_amdgcn_mfma_f32_16x16x32_bf16(af, bq[s], sf[c], 0, 0, 0);
            }
        }

        // scale (+ LSA diagonal mask, block-uniform branch)
        float p[4][4];
        float vmax = -3.0e38f;
        if (jt * 64 == q0) {
#pragma unroll
            for (int c = 0; c < 4; c++)
#pragma unroll
                for (int r = 0; r < 4; r++) {
                    float sv = sf[c][r] * scale2;
                    if (jt * 64 + c * 16 + g8 * 4 + r == qglob) sv = -3.0e37f;
                    p[c][r] = sv;
                    vmax = fmaxf(vmax, sv);
                }
        } else {
#pragma unroll
            for (int c = 0; c < 4; c++)
#pragma unroll
                for (int r = 0; r < 4; r++) {
                    const float sv = sf[c][r] * scale2;
                    p[c][r] = sv;
                    vmax = fmaxf(vmax, sv);
                }
        }
        vmax = fmaxf(vmax, __shfl_xor(vmax, 16));
        vmax = fmaxf(vmax, __shfl_xor(vmax, 32));

        // defer-max: only rescale when max grew past threshold (2^11 headroom, fp32-safe)
        if (!__all(vmax - m_s <= 11.0f)) {
            const float mnew = fmaxf(m_s, vmax);
            const float alpha = exp2f(m_s - mnew);
            m_s = mnew;
            l_s *= alpha;
#pragma unroll
            for (int r = 0; r < 4; r++) {
                const float a_r = __shfl(alpha, g8 * 4 + r, 64);
#pragma unroll
                for (int g = 0; g < 4; g++) accO[g][r] *= a_r;
            }
        }

        float tsum = 0.f;
#pragma unroll
        for (int c = 0; c < 4; c++)
#pragma unroll
            for (int r = 0; r < 4; r++) {
                const float pe = exp2f(p[c][r] - m_s);
                p[c][r] = pe;
                tsum += pe;
            }
        tsum += __shfl_xor(tsum, 16);
        tsum += __shfl_xor(tsum, 32);
        l_s += tsum;

        // pack P -> per-wave LDS in A-fragment layout (vector b64 writes)
#pragma unroll
        for (int c = 0; c < 4; c++) {
            u32 lo = (u32)f2b(p[c][0]) | ((u32)f2b(p[c][1]) << 16);
            u32 hi = (u32)f2b(p[c][2]) | ((u32)f2b(p[c][3]) << 16);
            uint2 pr; pr.x = lo; pr.y = hi;
            *reinterpret_cast<uint2*>(&Ps[w][qi * 80 + c * 16 + g8 * 4]) = pr;
        }

        // O += P V  (A = P, B-frag = V^T rows with XOR-swizzled chunks)
#pragma unroll
        for (int s = 0; s < 2; s++) {
            short8 ap = *reinterpret_cast<const short8*>(&Ps[w][qi * 80 + s * 32 + g8 * 8]);
#pragma unroll
            for (int g = 0; g < 4; g++) {
                const int vrow = g * 16 + qi;
                short8 bv = *reinterpret_cast<const short8*>(
                    &Vt[cur][vrow * 64 + (((s * 4 + g8) ^ (vrow & 7)) << 3)]);
                accO[g] = __builtin_amdgcn_mfma_f32_16x16x32_bf16(ap, bv, accO[g], 0, 0, 0);
            }
        }
        WAIT_LGKM0();
        __builtin_amdgcn_s_barrier();
        cur ^= 1;
    }

    // write O: lane row r holds q' = g8*4+r, dh = g*16+qi; l for q' is in lane q'
    const int bidx = bh / HEADS_, head = bh % HEADS_;
#pragma unroll
    for (int r = 0; r < 4; r++) {
        const float li = __shfl(l_s, g8 * 4 + r, 64);
        const float linv = 1.f / li;
        const int n = q0 + w * 16 + g8 * 4 + r;
#pragma unroll
        for (int g = 0; g < 4; g++) {
            const int dh = g * 16 + qi;
            o[((size_t)(bidx * NTOK + n)) * DIM_ + head * DH_ + dh] = f2b(accO[g][r] * linv);
        }
    }
}

// ---------------- host ----------------
extern "C" void kernel_launch(void* const* d_in, const int* in_sizes, int n_in,
                              void* d_out, int out_size, void* d_ws, size_t ws_size,
                              hipStream_t stream) {
    const float* x_in  = (const float*)d_in[0];
    const float* ln1_g = (const float*)d_in[1];
    const float* ln1_b = (const float*)d_in[2];
    const float* qkv_w = (const float*)d_in[3];
    const float* temp  = (const float*)d_in[4];
    const float* out_w = (const float*)d_in[5];
    const float* out_b = (const float*)d_in[6];
    const float* ln2_g = (const float*)d_in[7];
    const float* ln2_b = (const float*)d_in[8];
    const float* ff_w1 = (const float*)d_in[9];
    const float* ff_b1 = (const float*)d_in[10];
    const float* ff_w2 = (const float*)d_in[11];
    const float* ff_b2 = (const float*)d_in[12];

    char* ws = (char*)d_ws;
    size_t off = 0;
    auto alloc = [&](size_t bytes) -> void* {
        void* p = ws + off;
        off += (bytes + 255) & ~(size_t)255;
        return p;
    };
    u16* wt_qkv = (u16*)alloc((size_t)DEPTH_ * 1152 * 384 * 2);
    u16* wt_out = (u16*)alloc((size_t)DEPTH_ * 384 * 384 * 2);
    u16* wt_ff1 = (u16*)alloc((size_t)DEPTH_ * 1536 * 384 * 2);
    u16* wt_ff2 = (u16*)alloc((size_t)DEPTH_ * 384 * 1536 * 2);
    u16* H      = (u16*)alloc((size_t)MTOT * DIM_ * 2);
    u16* QKV    = (u16*)alloc((size_t)MTOT * MLP_ * 2);  // union: qkv (37.7MB) / mlp mid (50.3MB)
    u16* MID    = QKV;

    float* X = (float*)d_out;  // residual stream lives in d_out (fp32)

    hipMemcpyAsync(X, x_in, (size_t)MTOT * DIM_ * sizeof(float),
                   hipMemcpyDeviceToDevice, stream);

    transpose_w_kernel<<<dim3(6, 18, DEPTH_), 256, 0, stream>>>(qkv_w, wt_qkv, 384, 1152);
    transpose_w_kernel<<<dim3(6, 6, DEPTH_), 256, 0, stream>>>(out_w, wt_out, 384, 384);
    transpose_w_kernel<<<dim3(6, 24, DEPTH_), 256, 0, stream>>>(ff_w1, wt_ff1, 384, 1536);
    transpose_w_kernel<<<dim3(24, 6, DEPTH_), 256, 0, stream>>>(ff_w2, wt_ff2, 1536, 384);

    for (int layer = 0; layer < DEPTH_; layer++) {
        ln_kernel<<<4096, 256, 0, stream>>>(X, ln1_g + layer * DIM_, ln1_b + layer * DIM_, H);
        gemm_kernel<EPI_QKV><<<dim3(128, 9), 256, 0, stream>>>(
            H, wt_qkv + (size_t)layer * 1152 * 384, 384,
            nullptr, nullptr, nullptr, nullptr, 0, QKV);
        attn_kernel<<<dim3(96, 16), 256, 0, stream>>>(
            QKV, QKV + QKV_PLANE, QKV + 2 * QKV_PLANE, temp + layer, H);
        gemm_kernel<EPI_RES><<<dim3(128, 3), 256, 0, stream>>>(
            H, wt_out + (size_t)layer * 384 * 384, 384,
            out_b + layer * DIM_, X, X, nullptr, DIM_, nullptr);
        ln_kernel<<<4096, 256, 0, stream>>>(X, ln2_g + layer * DIM_, ln2_b + layer * DIM_, H);
        gemm_kernel<EPI_GELU><<<dim3(128, 12), 256, 0, stream>>>(
            H, wt_ff1 + (size_t)layer * 1536 * 384, 384,
            ff_b1 + layer * MLP_, nullptr, nullptr, MID, MLP_, nullptr);
        gemm_kernel<EPI_RES><<<dim3(128, 3), 256, 0, stream>>>(
            MID, wt_ff2 + (size_t)layer * 384 * 1536, 1536,
            ff_b2 + layer * DIM_, X, X, nullptr, DIM_, nullptr);
    }
}